// Round 5
// baseline (135.209 us; speedup 1.0000x reference)
//
#include <hip/hip_runtime.h>
#include <hip/hip_fp16.h>
#include <math.h>

#define B_SZ 64
#define P_SZ 256
#define N_SZ 4096
#define NCA 32                      // m_part chunks (128 n each)
#define A_ANC 0.08f
#define OMEGA_ANC 1256.6370614359172f

typedef _Float16 half8 __attribute__((ext_vector_type(8)));
typedef float floatx4 __attribute__((ext_vector_type(4)));

// K0: XP[p*N+n] = {cos(xi), sin(xi)} as half2. 1M elems, fully coalesced, ~0.5us.
__global__ __launch_bounds__(256) void k_xp(const float* __restrict__ xi,
                                            __half2* __restrict__ XP) {
    int idx = blockIdx.x * 256 + threadIdx.x;
    float s, c;
    __sincosf(xi[idx], &s, &c);
    XP[idx] = __floats2half2_rn(c, s);
}

// K_A: m_part via MFMA. m[b,p] = sum_n cos(phi[b,n])cos(xi[p,n]) + sin*sin
//  = f16 GEMM, M=64(b), N=256(p), K=8192 (cos/sin interleaved along k=2n+c).
// Wave computes a 16b x 16p tile over a 128-n chunk: 8 x mfma_f32_16x16x32_f16.
// A-frag (phi-trig) computed in registers (float4 load + 4 sincos per step);
// B-frag = verbatim 16B load of the XP row (already [cos,sin,cos,sin...]).
// No LDS, no __syncthreads. grid (64 tiles, 8 kgroups) x 4 waves = 2048 waves.
__global__ __launch_bounds__(256) void k_mpart_mfma(const float* __restrict__ phi,
                                                    const __half2* __restrict__ XP,
                                                    float* __restrict__ m_part) {
    const int bt = blockIdx.x & 3;          // b-tile (4 x 16)
    const int pt = blockIdx.x >> 2;         // p-tile (16 x 16)
    const int w  = threadIdx.x >> 6;        // wave -> k-subchunk
    const int lane = threadIdx.x & 63;
    const int m = lane & 15;                // A row (b) / B col (p)
    const int q = lane >> 4;                // quad

    const int c  = blockIdx.y * 4 + w;      // m_part chunk 0..31
    const int n0 = c * 128;                 // 128-n chunk
    const int b_row = bt * 16 + m;
    const int p_row = pt * 16 + m;

    floatx4 acc = {0.f, 0.f, 0.f, 0.f};
#pragma unroll
    for (int s = 0; s < 8; ++s) {
        const int nb = n0 + s * 16 + q * 4;             // this lane's 4 n's
        float4 ph = *(const float4*)&phi[b_row * N_SZ + nb];   // 16B, 16 rows x 64B
        half8 bf = *(const half8*)&XP[p_row * N_SZ + nb];      // B-frag verbatim
        half8 af;
        float ss, cc;
        __sincosf(ph.x, &ss, &cc); af[0] = (_Float16)cc; af[1] = (_Float16)ss;
        __sincosf(ph.y, &ss, &cc); af[2] = (_Float16)cc; af[3] = (_Float16)ss;
        __sincosf(ph.z, &ss, &cc); af[4] = (_Float16)cc; af[5] = (_Float16)ss;
        __sincosf(ph.w, &ss, &cc); af[6] = (_Float16)cc; af[7] = (_Float16)ss;
        acc = __builtin_amdgcn_mfma_f32_16x16x32_f16(af, bf, acc, 0, 0, 0);
    }
    // D: col(p)=lane&15, row(b)=q*4+r  [m89-verified layout]
#pragma unroll
    for (int r = 0; r < 4; ++r) {
        int b = bt * 16 + q * 4 + r;
        m_part[(c * 64 + b) * 256 + pt * 16 + m] = acc[r];
    }
}

// K_W: weights[b][p] = softmax_p( sum_c m_part[c][b][p] / N ). grid 64 x 256thr.
__global__ __launch_bounds__(256) void k_weights(const float* __restrict__ m_part,
                                                 float* __restrict__ weights) {
    const int b = blockIdx.x;
    const int tid = threadIdx.x;       // = p
    const int wv = tid >> 6;
    __shared__ float sred[8];

    float msum = 0.f;
#pragma unroll 8
    for (int c = 0; c < NCA; ++c)
        msum += m_part[(c * 64 + b) * 256 + tid];          // coalesced
    float logit = msum * (1.0f / 4096.0f);                 // BETA=1

    float v = logit;
    for (int o = 32; o > 0; o >>= 1) v = fmaxf(v, __shfl_xor(v, o));
    if ((tid & 63) == 0) sred[wv] = v;
    __syncthreads();
    float mx = fmaxf(fmaxf(sred[0], sred[1]), fmaxf(sred[2], sred[3]));
    float e = __expf(logit - mx);
    v = e;
    for (int o = 32; o > 0; o >>= 1) v += __shfl_xor(v, o);
    if ((tid & 63) == 0) sred[4 + wv] = v;
    __syncthreads();
    float s = sred[4] + sred[5] + sred[6] + sred[7];
    weights[b * 256 + tid] = e / s;
}

// K_B: coupling + anchor. grid (16 bt x 16 nc) = 256 blocks, 4 waves each.
// wave = one b x 256 n; lane owns 4 consecutive n (dwordx4 XP loads, 8 acc).
// Deep unroll keeps ~16 loads in flight to cover L2 latency at 1 wave/SIMD.
__global__ __launch_bounds__(256) void k_coupling(const __half2* __restrict__ XP,
                                                  const float* __restrict__ weights,
                                                  const float* __restrict__ phi,
                                                  const float* __restrict__ t_ptr,
                                                  float* __restrict__ out) {
    const int bt = blockIdx.x;   // 0..15
    const int nc = blockIdx.y;   // 0..15
    const int tid = threadIdx.x;
    const int w = tid >> 6;      // wave id = local b
    const int lane = tid & 63;

    __shared__ float wsh[4][256];
    for (int idx = tid; idx < 4 * 256; idx += 256) {
        int bb = idx >> 8, p = idx & 255;
        wsh[bb][p] = weights[(bt * 4 + bb) * 256 + p];     // coalesced
    }
    __syncthreads();

    const int n = nc * 256 + lane * 4;                     // lane's 4 n's
    const __half2* col = XP + n;
    float aC0 = 0.f, aS0 = 0.f, aC1 = 0.f, aS1 = 0.f;
    float aC2 = 0.f, aS2 = 0.f, aC3 = 0.f, aS3 = 0.f;

#pragma unroll 16
    for (int p = 0; p < 256; ++p) {
        uint4 v = *(const uint4*)&col[p * N_SZ];           // 16B/lane coalesced
        float wgt = wsh[w][p];                             // wave-uniform broadcast
        __half2 h0 = __builtin_bit_cast(__half2, v.x);
        __half2 h1 = __builtin_bit_cast(__half2, v.y);
        __half2 h2 = __builtin_bit_cast(__half2, v.z);
        __half2 h3 = __builtin_bit_cast(__half2, v.w);
        aC0 = fmaf(wgt, __low2float(h0), aC0); aS0 = fmaf(wgt, __high2float(h0), aS0);
        aC1 = fmaf(wgt, __low2float(h1), aC1); aS1 = fmaf(wgt, __high2float(h1), aS1);
        aC2 = fmaf(wgt, __low2float(h2), aC2); aS2 = fmaf(wgt, __high2float(h2), aS2);
        aC3 = fmaf(wgt, __low2float(h3), aC3); aS3 = fmaf(wgt, __high2float(h3), aS3);
    }

    const int b = bt * 4 + w;
    const float wt = OMEGA_ANC * t_ptr[0];
    float4 ph4 = *(const float4*)&phi[b * N_SZ + n];
    float s0, c0, s1, c1, s2, c2, s3, c3;
    __sincosf(ph4.x, &s0, &c0);
    __sincosf(ph4.y, &s1, &c1);
    __sincosf(ph4.z, &s2, &c2);
    __sincosf(ph4.w, &s3, &c3);
    float4 o;
    o.x = fmaf(A_ANC, __sinf(wt - ph4.x), s0 * aC0 - c0 * aS0);
    o.y = fmaf(A_ANC, __sinf(wt - ph4.y), s1 * aC1 - c1 * aS1);
    o.z = fmaf(A_ANC, __sinf(wt - ph4.z), s2 * aC2 - c2 * aS2);
    o.w = fmaf(A_ANC, __sinf(wt - ph4.w), s3 * aC3 - c3 * aS3);
    *(float4*)&out[b * N_SZ + n] = o;
}

extern "C" void kernel_launch(void* const* d_in, const int* in_sizes, int n_in,
                              void* d_out, int out_size, void* d_ws, size_t ws_size,
                              hipStream_t stream) {
    const float* t   = (const float*)d_in[0];
    const float* phi = (const float*)d_in[1];
    const float* xi  = (const float*)d_in[2];
    float* out = (float*)d_out;

    char* w = (char*)d_ws;
    __half2* XP    = (__half2*)w;                          // P*N half2      = 4 MB
    float* m_part  = (float*)(w + 4u * 1024 * 1024);       // 32*64*256 f32  = 2 MB
    float* weights = (float*)(w + 6u * 1024 * 1024);       // 64*256 f32     = 64 KB

    k_xp<<<(P_SZ * N_SZ) / 256, 256, 0, stream>>>(xi, XP);
    k_mpart_mfma<<<dim3(64, 8), 256, 0, stream>>>(phi, XP, m_part);
    k_weights<<<64, 256, 0, stream>>>(m_part, weights);
    k_coupling<<<dim3(16, 16), 256, 0, stream>>>(XP, weights, phi, t, out);
}

// Round 6
// 78.530 us; speedup vs baseline: 1.7218x; 1.7218x over previous
//
#include <hip/hip_runtime.h>
#include <hip/hip_fp16.h>
#include <math.h>
#include <stdint.h>

#define B_SZ 64
#define P_SZ 256
#define N_SZ 4096
#define NCA 32                      // m_part chunks (128 n each)
#define A_ANC 0.08f
#define OMEGA_ANC 1256.6370614359172f

typedef _Float16 half8 __attribute__((ext_vector_type(8)));
typedef float floatx4 __attribute__((ext_vector_type(4)));

// K0: XP[p*N+n] = {cos(xi), sin(xi)} as half2. 1M elems, coalesced, ~0.5us.
__global__ __launch_bounds__(256) void k_xp(const float* __restrict__ xi,
                                            __half2* __restrict__ XP) {
    int idx = blockIdx.x * 256 + threadIdx.x;
    float s, c;
    __sincosf(xi[idx], &s, &c);
    XP[idx] = __floats2half2_rn(c, s);
}

// K_A: m_part via MFMA (verified in R5: absmax unchanged).
// m[b,p] = sum_n cos(phi-xi) = f16 GEMM, K=8192 cos/sin-interleaved.
__global__ __launch_bounds__(256) void k_mpart_mfma(const float* __restrict__ phi,
                                                    const __half2* __restrict__ XP,
                                                    float* __restrict__ m_part) {
    const int bt = blockIdx.x & 3;          // b-tile (4 x 16)
    const int pt = blockIdx.x >> 2;         // p-tile (16 x 16)
    const int w  = threadIdx.x >> 6;
    const int lane = threadIdx.x & 63;
    const int m = lane & 15;
    const int q = lane >> 4;

    const int c  = blockIdx.y * 4 + w;      // m_part chunk 0..31
    const int n0 = c * 128;
    const int b_row = bt * 16 + m;
    const int p_row = pt * 16 + m;

    floatx4 acc = {0.f, 0.f, 0.f, 0.f};
#pragma unroll
    for (int s = 0; s < 8; ++s) {
        const int nb = n0 + s * 16 + q * 4;
        float4 ph = *(const float4*)&phi[b_row * N_SZ + nb];
        half8 bf = *(const half8*)&XP[p_row * N_SZ + nb];
        half8 af;
        float ss, cc;
        __sincosf(ph.x, &ss, &cc); af[0] = (_Float16)cc; af[1] = (_Float16)ss;
        __sincosf(ph.y, &ss, &cc); af[2] = (_Float16)cc; af[3] = (_Float16)ss;
        __sincosf(ph.z, &ss, &cc); af[4] = (_Float16)cc; af[5] = (_Float16)ss;
        __sincosf(ph.w, &ss, &cc); af[6] = (_Float16)cc; af[7] = (_Float16)ss;
        acc = __builtin_amdgcn_mfma_f32_16x16x32_f16(af, bf, acc, 0, 0, 0);
    }
#pragma unroll
    for (int r = 0; r < 4; ++r) {
        int b = bt * 16 + q * 4 + r;
        m_part[(c * 64 + b) * 256 + pt * 16 + m] = acc[r];
    }
}

// K_W: softmax over p; emits f16 weight table Wh[b][p] (A-operand for K_B).
__global__ __launch_bounds__(256) void k_weights(const float* __restrict__ m_part,
                                                 _Float16* __restrict__ Wh) {
    const int b = blockIdx.x;
    const int tid = threadIdx.x;       // = p
    const int wv = tid >> 6;
    __shared__ float sred[8];

    float msum = 0.f;
#pragma unroll 8
    for (int c = 0; c < NCA; ++c)
        msum += m_part[(c * 64 + b) * 256 + tid];          // coalesced
    float logit = msum * (1.0f / 4096.0f);                 // BETA=1

    float v = logit;
    for (int o = 32; o > 0; o >>= 1) v = fmaxf(v, __shfl_xor(v, o));
    if ((tid & 63) == 0) sred[wv] = v;
    __syncthreads();
    float mx = fmaxf(fmaxf(sred[0], sred[1]), fmaxf(sred[2], sred[3]));
    float e = __expf(logit - mx);
    v = e;
    for (int o = 32; o > 0; o >>= 1) v += __shfl_xor(v, o);
    if ((tid & 63) == 0) sred[4 + wv] = v;
    __syncthreads();
    float s = sred[4] + sred[5] + sred[6] + sred[7];
    Wh[b * 256 + tid] = (_Float16)(e / s);
}

// K_B: coupling via MFMA. out[b,n]: C[b][col] = sum_p Wh[b,p] * Xcomp[p][n],
// col = 2n+comp (cos/sin folded into the column dim). K=256(p) = 8 mfmas/wave.
// A-frag: 16B row load of Wh. B-frag: 8 dword gathers from XP, lo/hi extract.
// Epilogue: even col holds aC, odd holds aS of same n -> pair via shfl_xor(1).
// grid (4 m-tiles, 128) x 4 waves = 2048 waves = 8/CU, no LDS, no barriers.
__global__ __launch_bounds__(256) void k_coupling_mfma(const __half2* __restrict__ XP,
                                                       const _Float16* __restrict__ Wh,
                                                       const float* __restrict__ phi,
                                                       const float* __restrict__ t_ptr,
                                                       float* __restrict__ out) {
    const int mt = blockIdx.x;                             // 0..3
    const int ct = blockIdx.y * 4 + (threadIdx.x >> 6);    // 0..511
    const int lane = threadIdx.x & 63;
    const int cl = lane & 15;
    const int q  = lane >> 4;

    const int col  = ct * 16 + cl;                         // 0..8191
    const int n    = col >> 1;
    const int comp = col & 1;                              // 0=cos(lo), 1=sin(hi)

    const _Float16* wrow = Wh + (mt * 16 + cl) * 256;      // A row b = mt*16+cl
    const uint32_t* xp32 = (const uint32_t*)XP;

    floatx4 acc = {0.f, 0.f, 0.f, 0.f};
#pragma unroll
    for (int s = 0; s < 8; ++s) {
        const int k0 = s * 32 + q * 8;                     // this lane's first p
        half8 af = *(const half8*)&wrow[k0];               // 16B, L1/L2-hot (32KB)
        half8 bf;
#pragma unroll
        for (int j = 0; j < 8; ++j) {
            uint32_t v = xp32[(k0 + j) * N_SZ + n];        // {cos,sin} dword
            uint16_t h = (uint16_t)(comp ? (v >> 16) : (v & 0xffffu));
            bf[j] = __builtin_bit_cast(_Float16, h);
        }
        acc = __builtin_amdgcn_mfma_f32_16x16x32_f16(af, bf, acc, 0, 0, 0);
    }

    // D: col=lane&15, row(b-local)=q*4+r [verified layout]
    float aS0 = __shfl_xor(acc[0], 1);
    float aS1 = __shfl_xor(acc[1], 1);
    float aS2 = __shfl_xor(acc[2], 1);
    float aS3 = __shfl_xor(acc[3], 1);
    if (!comp) {
        const float wt = OMEGA_ANC * t_ptr[0];
        float aC[4] = {acc[0], acc[1], acc[2], acc[3]};
        float aS[4] = {aS0, aS1, aS2, aS3};
#pragma unroll
        for (int r = 0; r < 4; ++r) {
            int b = mt * 16 + q * 4 + r;
            float ph = phi[b * N_SZ + n];
            float ss, cc;
            __sincosf(ph, &ss, &cc);
            out[b * N_SZ + n] =
                fmaf(A_ANC, __sinf(wt - ph), ss * aC[r] - cc * aS[r]);
        }
    }
}

extern "C" void kernel_launch(void* const* d_in, const int* in_sizes, int n_in,
                              void* d_out, int out_size, void* d_ws, size_t ws_size,
                              hipStream_t stream) {
    const float* t   = (const float*)d_in[0];
    const float* phi = (const float*)d_in[1];
    const float* xi  = (const float*)d_in[2];
    float* out = (float*)d_out;

    char* w = (char*)d_ws;
    __half2* XP     = (__half2*)w;                         // P*N half2     = 4 MB
    float* m_part   = (float*)(w + 4u * 1024 * 1024);      // 32*64*256 f32 = 2 MB
    _Float16* Wh    = (_Float16*)(w + 6u * 1024 * 1024);   // 64*256 f16    = 32 KB

    k_xp<<<(P_SZ * N_SZ) / 256, 256, 0, stream>>>(xi, XP);
    k_mpart_mfma<<<dim3(64, 8), 256, 0, stream>>>(phi, XP, m_part);
    k_weights<<<64, 256, 0, stream>>>(m_part, Wh);
    k_coupling_mfma<<<dim3(4, 128), 256, 0, stream>>>(XP, Wh, phi, t, out);
}

// Round 7
// 76.249 us; speedup vs baseline: 1.7733x; 1.0299x over previous
//
#include <hip/hip_runtime.h>
#include <hip/hip_fp16.h>
#include <math.h>
#include <stdint.h>

#define B_SZ 64
#define P_SZ 256
#define N_SZ 4096
#define NCA 32                      // m_part chunks (128 n each)
#define A_ANC 0.08f
#define OMEGA_ANC 1256.6370614359172f

typedef _Float16 half8 __attribute__((ext_vector_type(8)));
typedef float floatx4 __attribute__((ext_vector_type(4)));

__device__ __forceinline__ uint32_t permsel(uint32_t hi, uint32_t lo, uint32_t sel) {
#if __has_builtin(__builtin_amdgcn_perm)
    return __builtin_amdgcn_perm(hi, lo, sel);
#else
    unsigned long long v = ((unsigned long long)hi << 32) | lo;
    uint32_t r = 0;
#pragma unroll
    for (int i = 0; i < 4; ++i)
        r |= (uint32_t)((v >> (8 * ((sel >> (8 * i)) & 7))) & 0xff) << (8 * i);
    return r;
#endif
}

// K_A: m_part via MFMA; trig computed in-register for BOTH operands.
//  m[b,p] = sum_n cos(phi-xi) = f16 GEMM, K=8192 cos/sin-interleaved (R5/R6-verified).
//  bt==0 waves additionally store their B-frags to XPT[n][p] (half2 {cos,sin}):
//  each (n,p) covered exactly once; store = 64 lanes x 4B = 4 dense 64B segments.
// grid (64, 8) x 4 waves = 2048 waves = 8/CU. No LDS, no barriers.
__global__ __launch_bounds__(256) void k_mpart_mfma(const float* __restrict__ phi,
                                                    const float* __restrict__ xi,
                                                    uint32_t* __restrict__ XPT,
                                                    float* __restrict__ m_part) {
    const int bt = blockIdx.x & 3;          // b-tile (4 x 16)
    const int pt = blockIdx.x >> 2;         // p-tile (16 x 16)
    const int w  = threadIdx.x >> 6;
    const int lane = threadIdx.x & 63;
    const int m = lane & 15;
    const int q = lane >> 4;

    const int c  = blockIdx.y * 4 + w;      // m_part chunk 0..31
    const int n0 = c * 128;
    const int b_row = bt * 16 + m;
    const int p_row = pt * 16 + m;

    floatx4 acc = {0.f, 0.f, 0.f, 0.f};
#pragma unroll
    for (int s = 0; s < 8; ++s) {
        const int nb = n0 + s * 16 + q * 4;                    // this lane's 4 n's
        float4 ph = *(const float4*)&phi[b_row * N_SZ + nb];   // A source
        float4 xv = *(const float4*)&xi[p_row * N_SZ + nb];    // B source
        half8 af, bf;
        float ss, cc;
        __sincosf(ph.x, &ss, &cc); af[0] = (_Float16)cc; af[1] = (_Float16)ss;
        __sincosf(ph.y, &ss, &cc); af[2] = (_Float16)cc; af[3] = (_Float16)ss;
        __sincosf(ph.z, &ss, &cc); af[4] = (_Float16)cc; af[5] = (_Float16)ss;
        __sincosf(ph.w, &ss, &cc); af[6] = (_Float16)cc; af[7] = (_Float16)ss;
        __sincosf(xv.x, &ss, &cc); bf[0] = (_Float16)cc; bf[1] = (_Float16)ss;
        __sincosf(xv.y, &ss, &cc); bf[2] = (_Float16)cc; bf[3] = (_Float16)ss;
        __sincosf(xv.z, &ss, &cc); bf[4] = (_Float16)cc; bf[5] = (_Float16)ss;
        __sincosf(xv.w, &ss, &cc); bf[6] = (_Float16)cc; bf[7] = (_Float16)ss;
        if (bt == 0) {                                         // wave-uniform branch
            uint4 bi = __builtin_bit_cast(uint4, bf);
            XPT[(nb + 0) * P_SZ + p_row] = bi.x;
            XPT[(nb + 1) * P_SZ + p_row] = bi.y;
            XPT[(nb + 2) * P_SZ + p_row] = bi.z;
            XPT[(nb + 3) * P_SZ + p_row] = bi.w;
        }
        acc = __builtin_amdgcn_mfma_f32_16x16x32_f16(af, bf, acc, 0, 0, 0);
    }
#pragma unroll
    for (int r = 0; r < 4; ++r) {
        int b = bt * 16 + q * 4 + r;
        m_part[(c * 64 + b) * 256 + pt * 16 + m] = acc[r];
    }
}

// K_W: softmax over p; emits f16 weight table Wh[b][p] (A-operand for K_B).
__global__ __launch_bounds__(256) void k_weights(const float* __restrict__ m_part,
                                                 _Float16* __restrict__ Wh) {
    const int b = blockIdx.x;
    const int tid = threadIdx.x;       // = p
    const int wv = tid >> 6;
    __shared__ float sred[8];

    float msum = 0.f;
#pragma unroll 8
    for (int c = 0; c < NCA; ++c)
        msum += m_part[(c * 64 + b) * 256 + tid];          // coalesced
    float logit = msum * (1.0f / 4096.0f);                 // BETA=1

    float v = logit;
    for (int o = 32; o > 0; o >>= 1) v = fmaxf(v, __shfl_xor(v, o));
    if ((tid & 63) == 0) sred[wv] = v;
    __syncthreads();
    float mx = fmaxf(fmaxf(sred[0], sred[1]), fmaxf(sred[2], sred[3]));
    float e = __expf(logit - mx);
    v = e;
    for (int o = 32; o > 0; o >>= 1) v += __shfl_xor(v, o);
    if ((tid & 63) == 0) sred[4 + wv] = v;
    __syncthreads();
    float s = sred[4] + sred[5] + sred[6] + sred[7];
    Wh[b * 256 + tid] = (_Float16)(e / s);
}

// K_B: coupling via MFMA, col = 2n+comp (R6-verified structure), but B-frags now
// load DENSE from XPT[n][p]: lane's 8 k's (p=k0..k0+7, fixed n) = 2 x dwordx4,
// comp extraction via v_perm_b32 (lo-halves sel 0x05040100 / hi 0x07060302).
// Epilogue: even/odd col pair (aC,aS) via shfl_xor(1) [R6-verified].
// grid (4 m-tiles, 128) x 4 waves = 2048 waves = 8/CU, no LDS, no barriers.
__global__ __launch_bounds__(256) void k_coupling_mfma(const uint32_t* __restrict__ XPT,
                                                       const _Float16* __restrict__ Wh,
                                                       const float* __restrict__ phi,
                                                       const float* __restrict__ t_ptr,
                                                       float* __restrict__ out) {
    const int mt = blockIdx.x;                             // 0..3
    const int ct = blockIdx.y * 4 + (threadIdx.x >> 6);    // 0..511
    const int lane = threadIdx.x & 63;
    const int cl = lane & 15;
    const int q  = lane >> 4;

    const int col  = ct * 16 + cl;                         // 0..8191
    const int n    = col >> 1;
    const int comp = col & 1;                              // 0=cos(lo), 1=sin(hi)
    const uint32_t sel = comp ? 0x07060302u : 0x05040100u;

    const _Float16* wrow = Wh + (mt * 16 + cl) * 256;      // A row b = mt*16+cl
    const uint32_t* xrow = XPT + n * P_SZ;                 // dense: 256 {cos,sin} dwords

    floatx4 acc = {0.f, 0.f, 0.f, 0.f};
#pragma unroll
    for (int s = 0; s < 8; ++s) {
        const int k0 = s * 32 + q * 8;                     // this lane's first p
        half8 af = *(const half8*)&wrow[k0];               // 16B, L1-hot (32KB table)
        uint4 v0 = *(const uint4*)&xrow[k0];               // p = k0..k0+3
        uint4 v1 = *(const uint4*)&xrow[k0 + 4];           // p = k0+4..k0+7
        uint4 bi;
        bi.x = permsel(v0.y, v0.x, sel);                   // {h(k0),   h(k0+1)}
        bi.y = permsel(v0.w, v0.z, sel);
        bi.z = permsel(v1.y, v1.x, sel);
        bi.w = permsel(v1.w, v1.z, sel);
        half8 bf = __builtin_bit_cast(half8, bi);
        acc = __builtin_amdgcn_mfma_f32_16x16x32_f16(af, bf, acc, 0, 0, 0);
    }

    // D: col=lane&15, row(b-local)=q*4+r [verified]; pair cos/sin via xor(1)
    float aS0 = __shfl_xor(acc[0], 1);
    float aS1 = __shfl_xor(acc[1], 1);
    float aS2 = __shfl_xor(acc[2], 1);
    float aS3 = __shfl_xor(acc[3], 1);
    if (!comp) {
        const float wt = OMEGA_ANC * t_ptr[0];
        float aC[4] = {acc[0], acc[1], acc[2], acc[3]};
        float aS[4] = {aS0, aS1, aS2, aS3};
#pragma unroll
        for (int r = 0; r < 4; ++r) {
            int b = mt * 16 + q * 4 + r;
            float ph = phi[b * N_SZ + n];
            float ss, cc;
            __sincosf(ph, &ss, &cc);
            out[b * N_SZ + n] =
                fmaf(A_ANC, __sinf(wt - ph), ss * aC[r] - cc * aS[r]);
        }
    }
}

extern "C" void kernel_launch(void* const* d_in, const int* in_sizes, int n_in,
                              void* d_out, int out_size, void* d_ws, size_t ws_size,
                              hipStream_t stream) {
    const float* t   = (const float*)d_in[0];
    const float* phi = (const float*)d_in[1];
    const float* xi  = (const float*)d_in[2];
    float* out = (float*)d_out;

    char* w = (char*)d_ws;
    uint32_t* XPT   = (uint32_t*)w;                        // N*P dwords    = 4 MB
    float* m_part   = (float*)(w + 4u * 1024 * 1024);      // 32*64*256 f32 = 2 MB
    _Float16* Wh    = (_Float16*)(w + 6u * 1024 * 1024);   // 64*256 f16    = 32 KB

    k_mpart_mfma<<<dim3(64, 8), 256, 0, stream>>>(phi, xi, XPT, m_part);
    k_weights<<<64, 256, 0, stream>>>(m_part, Wh);
    k_coupling_mfma<<<dim3(4, 128), 256, 0, stream>>>(XPT, Wh, phi, t, out);
}

// Round 8
// 75.915 us; speedup vs baseline: 1.7811x; 1.0044x over previous
//
#include <hip/hip_runtime.h>
#include <hip/hip_fp16.h>
#include <math.h>
#include <stdint.h>

#define B_SZ 64
#define P_SZ 256
#define N_SZ 4096
#define NCA 32                      // m_part chunks (128 n each)
#define A_ANC 0.08f
#define OMEGA_ANC 1256.6370614359172f

typedef _Float16 half8 __attribute__((ext_vector_type(8)));
typedef float floatx4 __attribute__((ext_vector_type(4)));

__device__ __forceinline__ uint32_t permsel(uint32_t hi, uint32_t lo, uint32_t sel) {
#if __has_builtin(__builtin_amdgcn_perm)
    return __builtin_amdgcn_perm(hi, lo, sel);
#else
    unsigned long long v = ((unsigned long long)hi << 32) | lo;
    uint32_t r = 0;
#pragma unroll
    for (int i = 0; i < 4; ++i)
        r |= (uint32_t)((v >> (8 * ((sel >> (8 * i)) & 7))) & 0xff) << (8 * i);
    return r;
#endif
}

// K_A: m_part via MFMA; trig computed in-register for BOTH operands (R7-verified).
// bt==0 waves store their B-frags to XPT[n][p] (half2 {cos,sin}), each (n,p) once.
// grid (64, 8) x 4 waves = 2048 waves = 8/CU. No LDS, no barriers.
__global__ __launch_bounds__(256) void k_mpart_mfma(const float* __restrict__ phi,
                                                    const float* __restrict__ xi,
                                                    uint32_t* __restrict__ XPT,
                                                    float* __restrict__ m_part) {
    const int bt = blockIdx.x & 3;          // b-tile (4 x 16)
    const int pt = blockIdx.x >> 2;         // p-tile (16 x 16)
    const int w  = threadIdx.x >> 6;
    const int lane = threadIdx.x & 63;
    const int m = lane & 15;
    const int q = lane >> 4;

    const int c  = blockIdx.y * 4 + w;      // m_part chunk 0..31
    const int n0 = c * 128;
    const int b_row = bt * 16 + m;
    const int p_row = pt * 16 + m;

    floatx4 acc = {0.f, 0.f, 0.f, 0.f};
#pragma unroll
    for (int s = 0; s < 8; ++s) {
        const int nb = n0 + s * 16 + q * 4;                    // this lane's 4 n's
        float4 ph = *(const float4*)&phi[b_row * N_SZ + nb];   // A source (line-dense)
        float4 xv = *(const float4*)&xi[p_row * N_SZ + nb];    // B source (line-dense)
        half8 af, bf;
        float ss, cc;
        __sincosf(ph.x, &ss, &cc); af[0] = (_Float16)cc; af[1] = (_Float16)ss;
        __sincosf(ph.y, &ss, &cc); af[2] = (_Float16)cc; af[3] = (_Float16)ss;
        __sincosf(ph.z, &ss, &cc); af[4] = (_Float16)cc; af[5] = (_Float16)ss;
        __sincosf(ph.w, &ss, &cc); af[6] = (_Float16)cc; af[7] = (_Float16)ss;
        __sincosf(xv.x, &ss, &cc); bf[0] = (_Float16)cc; bf[1] = (_Float16)ss;
        __sincosf(xv.y, &ss, &cc); bf[2] = (_Float16)cc; bf[3] = (_Float16)ss;
        __sincosf(xv.z, &ss, &cc); bf[4] = (_Float16)cc; bf[5] = (_Float16)ss;
        __sincosf(xv.w, &ss, &cc); bf[6] = (_Float16)cc; bf[7] = (_Float16)ss;
        if (bt == 0) {                                         // wave-uniform branch
            uint4 bi = __builtin_bit_cast(uint4, bf);
            XPT[(nb + 0) * P_SZ + p_row] = bi.x;
            XPT[(nb + 1) * P_SZ + p_row] = bi.y;
            XPT[(nb + 2) * P_SZ + p_row] = bi.z;
            XPT[(nb + 3) * P_SZ + p_row] = bi.w;
        }
        acc = __builtin_amdgcn_mfma_f32_16x16x32_f16(af, bf, acc, 0, 0, 0);
    }
#pragma unroll
    for (int r = 0; r < 4; ++r) {
        int b = bt * 16 + q * 4 + r;
        m_part[(c * 64 + b) * 256 + pt * 16 + m] = acc[r];
    }
}

// K_W: softmax over p; emits f16 weight table Wh[b][p] (A-operand for K_B).
// Full unroll: all 32 chunk-loads independent -> one latency batch.
__global__ __launch_bounds__(256) void k_weights(const float* __restrict__ m_part,
                                                 _Float16* __restrict__ Wh) {
    const int b = blockIdx.x;
    const int tid = threadIdx.x;       // = p
    const int wv = tid >> 6;
    __shared__ float sred[8];

    float acc[NCA];
#pragma unroll
    for (int c = 0; c < NCA; ++c)
        acc[c] = m_part[(c * 64 + b) * 256 + tid];         // 32 independent loads
    float msum = 0.f;
#pragma unroll
    for (int c = 0; c < NCA; ++c) msum += acc[c];
    float logit = msum * (1.0f / 4096.0f);                 // BETA=1

    float v = logit;
    for (int o = 32; o > 0; o >>= 1) v = fmaxf(v, __shfl_xor(v, o));
    if ((tid & 63) == 0) sred[wv] = v;
    __syncthreads();
    float mx = fmaxf(fmaxf(sred[0], sred[1]), fmaxf(sred[2], sred[3]));
    float e = __expf(logit - mx);
    v = e;
    for (int o = 32; o > 0; o >>= 1) v += __shfl_xor(v, o);
    if ((tid & 63) == 0) sred[4 + wv] = v;
    __syncthreads();
    float s = sred[4] + sred[5] + sred[6] + sred[7];
    Wh[b * 256 + tid] = (_Float16)(e / s);
}

// K_B: coupling via MFMA (R6/R7-verified math), B-operand staged through LDS.
// Block = (mt, ct-group of 4): stages 32 XPT rows (32KB) ROW-DENSE (each wave
// instr = one full 1KB row), then B-frags come from LDS (2x ds_read_b128 + perm).
// Chip line-traffic for XPT: 128MB (R7, 4x sparse) -> 16MB dense.
// grid (4, 128) = 512 blocks, 33KB LDS, 8 waves/CU.
__global__ __launch_bounds__(256) void k_coupling_mfma(const uint32_t* __restrict__ XPT,
                                                       const _Float16* __restrict__ Wh,
                                                       const float* __restrict__ phi,
                                                       const float* __restrict__ t_ptr,
                                                       float* __restrict__ out) {
    const int mt = blockIdx.x;                             // 0..3
    const int ctg = blockIdx.y;                            // 0..127
    const int tid = threadIdx.x;
    const int w = tid >> 6;
    const int lane = tid & 63;
    const int cl = lane & 15;
    const int q  = lane >> 4;

    __shared__ uint32_t xs[32][260];                       // 32 rows, 1KB + 16B pad

    const int n0 = ctg * 32;
    // stage: 8 iters, each wave loads one full row per iter (1KB dense)
#pragma unroll
    for (int it = 0; it < 8; ++it) {
        int i = tid + it * 256;
        int row = i >> 6, seg = i & 63;
        uint4 v = *(const uint4*)&XPT[(n0 + row) * P_SZ + seg * 4];
        *(uint4*)&xs[row][seg * 4] = v;
    }
    __syncthreads();

    const int ct  = ctg * 4 + w;
    const int col = ct * 16 + cl;                          // 0..8191
    const int n   = col >> 1;
    const int n_l = w * 8 + (cl >> 1);                     // n - n0
    const int comp = col & 1;                              // 0=cos(lo), 1=sin(hi)
    const uint32_t sel = comp ? 0x07060302u : 0x05040100u;

    const _Float16* wrow = Wh + (mt * 16 + cl) * 256;      // A row b = mt*16+cl

    floatx4 acc = {0.f, 0.f, 0.f, 0.f};
#pragma unroll
    for (int s = 0; s < 8; ++s) {
        const int k0 = s * 32 + q * 8;                     // this lane's first p
        half8 af = *(const half8*)&wrow[k0];               // 16B, L2-hot (32KB table)
        uint4 v0 = *(const uint4*)&xs[n_l][k0];            // ds_read_b128
        uint4 v1 = *(const uint4*)&xs[n_l][k0 + 4];
        uint4 bi;
        bi.x = permsel(v0.y, v0.x, sel);
        bi.y = permsel(v0.w, v0.z, sel);
        bi.z = permsel(v1.y, v1.x, sel);
        bi.w = permsel(v1.w, v1.z, sel);
        half8 bf = __builtin_bit_cast(half8, bi);
        acc = __builtin_amdgcn_mfma_f32_16x16x32_f16(af, bf, acc, 0, 0, 0);
    }

    // D: col=lane&15, row(b-local)=q*4+r [verified]; pair cos/sin via xor(1)
    float aS0 = __shfl_xor(acc[0], 1);
    float aS1 = __shfl_xor(acc[1], 1);
    float aS2 = __shfl_xor(acc[2], 1);
    float aS3 = __shfl_xor(acc[3], 1);
    if (!comp) {
        const float wt = OMEGA_ANC * t_ptr[0];
        float aC[4] = {acc[0], acc[1], acc[2], acc[3]};
        float aS[4] = {aS0, aS1, aS2, aS3};
#pragma unroll
        for (int r = 0; r < 4; ++r) {
            int b = mt * 16 + q * 4 + r;
            float ph = phi[b * N_SZ + n];
            float ss, cc;
            __sincosf(ph, &ss, &cc);
            out[b * N_SZ + n] =
                fmaf(A_ANC, __sinf(wt - ph), ss * aC[r] - cc * aS[r]);
        }
    }
}

extern "C" void kernel_launch(void* const* d_in, const int* in_sizes, int n_in,
                              void* d_out, int out_size, void* d_ws, size_t ws_size,
                              hipStream_t stream) {
    const float* t   = (const float*)d_in[0];
    const float* phi = (const float*)d_in[1];
    const float* xi  = (const float*)d_in[2];
    float* out = (float*)d_out;

    char* w = (char*)d_ws;
    uint32_t* XPT   = (uint32_t*)w;                        // N*P dwords    = 4 MB
    float* m_part   = (float*)(w + 4u * 1024 * 1024);      // 32*64*256 f32 = 2 MB
    _Float16* Wh    = (_Float16*)(w + 6u * 1024 * 1024);   // 64*256 f16    = 32 KB

    k_mpart_mfma<<<dim3(64, 8), 256, 0, stream>>>(phi, xi, XPT, m_part);
    k_weights<<<64, 256, 0, stream>>>(m_part, Wh);
    k_coupling_mfma<<<dim3(4, 128), 256, 0, stream>>>(XPT, Wh, phi, t, out);
}

// Round 9
// 75.899 us; speedup vs baseline: 1.7814x; 1.0002x over previous
//
#include <hip/hip_runtime.h>
#include <hip/hip_fp16.h>
#include <math.h>
#include <stdint.h>

#define B_SZ 64
#define P_SZ 256
#define N_SZ 4096
#define NCA 32                      // m_part chunks (128 n each)
#define A_ANC 0.08f
#define OMEGA_ANC 1256.6370614359172f
#define INV_2PI 0.15915494309189535f

typedef _Float16 half8 __attribute__((ext_vector_type(8)));
typedef _Float16 half2v __attribute__((ext_vector_type(2)));
typedef float floatx4 __attribute__((ext_vector_type(4)));

// raw v_sin/v_cos: D = sin(2*pi*r). Inputs here are pre-scaled by 1/2pi.
__device__ __forceinline__ float vsin_r(float r) {
#if __has_builtin(__builtin_amdgcn_sinf)
    return __builtin_amdgcn_sinf(r);
#else
    return __sinf(r * 6.283185307179586f);
#endif
}
__device__ __forceinline__ float vcos_r(float r) {
#if __has_builtin(__builtin_amdgcn_cosf)
    return __builtin_amdgcn_cosf(r);
#else
    return __cosf(r * 6.283185307179586f);
#endif
}
__device__ __forceinline__ float vfract(float r) {
#if __has_builtin(__builtin_amdgcn_fractf)
    return __builtin_amdgcn_fractf(r);
#else
    return r - floorf(r);
#endif
}
// {cos(x), sin(x)} packed to half2 dword in one v_cvt_pkrtz; x in [0, 2pi)
__device__ __forceinline__ uint32_t cs_pack(float x) {
    float r = x * INV_2PI;
    return __builtin_bit_cast(uint32_t,
        __builtin_amdgcn_cvt_pkrtz(vcos_r(r), vsin_r(r)));
}

__device__ __forceinline__ uint32_t permsel(uint32_t hi, uint32_t lo, uint32_t sel) {
#if __has_builtin(__builtin_amdgcn_perm)
    return __builtin_amdgcn_perm(hi, lo, sel);
#else
    unsigned long long v = ((unsigned long long)hi << 32) | lo;
    uint32_t r = 0;
#pragma unroll
    for (int i = 0; i < 4; ++i)
        r |= (uint32_t)((v >> (8 * ((sel >> (8 * i)) & 7))) & 0xff) << (8 * i);
    return r;
#endif
}

// K_A: m_part via MFMA; trig in-register via raw v_sin/v_cos (args in [0,2pi)).
// bt==0 waves store B-frags to XPT[n][p] ({cos,sin} half2 dword), each (n,p) once.
// grid (64, 8) x 4 waves = 2048 waves = 8/CU. No LDS, no barriers.
__global__ __launch_bounds__(256) void k_mpart_mfma(const float* __restrict__ phi,
                                                    const float* __restrict__ xi,
                                                    uint32_t* __restrict__ XPT,
                                                    float* __restrict__ m_part) {
    const int bt = blockIdx.x & 3;          // b-tile (4 x 16)
    const int pt = blockIdx.x >> 2;         // p-tile (16 x 16)
    const int w  = threadIdx.x >> 6;
    const int lane = threadIdx.x & 63;
    const int m = lane & 15;
    const int q = lane >> 4;

    const int c  = blockIdx.y * 4 + w;      // m_part chunk 0..31
    const int n0 = c * 128;
    const int b_row = bt * 16 + m;
    const int p_row = pt * 16 + m;

    floatx4 acc = {0.f, 0.f, 0.f, 0.f};
#pragma unroll
    for (int s = 0; s < 8; ++s) {
        const int nb = n0 + s * 16 + q * 4;                    // this lane's 4 n's
        float4 ph = *(const float4*)&phi[b_row * N_SZ + nb];   // A source (line-dense)
        float4 xv = *(const float4*)&xi[p_row * N_SZ + nb];    // B source (line-dense)
        uint4 ai, bi;
        ai.x = cs_pack(ph.x); ai.y = cs_pack(ph.y);
        ai.z = cs_pack(ph.z); ai.w = cs_pack(ph.w);
        bi.x = cs_pack(xv.x); bi.y = cs_pack(xv.y);
        bi.z = cs_pack(xv.z); bi.w = cs_pack(xv.w);
        if (bt == 0) {                                         // wave-uniform branch
            XPT[(nb + 0) * P_SZ + p_row] = bi.x;
            XPT[(nb + 1) * P_SZ + p_row] = bi.y;
            XPT[(nb + 2) * P_SZ + p_row] = bi.z;
            XPT[(nb + 3) * P_SZ + p_row] = bi.w;
        }
        half8 af = __builtin_bit_cast(half8, ai);
        half8 bf = __builtin_bit_cast(half8, bi);
        acc = __builtin_amdgcn_mfma_f32_16x16x32_f16(af, bf, acc, 0, 0, 0);
    }
#pragma unroll
    for (int r = 0; r < 4; ++r) {
        int b = bt * 16 + q * 4 + r;
        m_part[(c * 64 + b) * 256 + pt * 16 + m] = acc[r];
    }
}

// K_W: softmax over p; emits f16 weight table Wh[b][p] (A-operand for K_B).
__global__ __launch_bounds__(256) void k_weights(const float* __restrict__ m_part,
                                                 _Float16* __restrict__ Wh) {
    const int b = blockIdx.x;
    const int tid = threadIdx.x;       // = p
    const int wv = tid >> 6;
    __shared__ float sred[8];

    float acc[NCA];
#pragma unroll
    for (int c = 0; c < NCA; ++c)
        acc[c] = m_part[(c * 64 + b) * 256 + tid];         // 32 independent loads
    float msum = 0.f;
#pragma unroll
    for (int c = 0; c < NCA; ++c) msum += acc[c];
    float logit = msum * (1.0f / 4096.0f);                 // BETA=1

    float v = logit;
    for (int o = 32; o > 0; o >>= 1) v = fmaxf(v, __shfl_xor(v, o));
    if ((tid & 63) == 0) sred[wv] = v;
    __syncthreads();
    float mx = fmaxf(fmaxf(sred[0], sred[1]), fmaxf(sred[2], sred[3]));
    float e = __expf(logit - mx);
    v = e;
    for (int o = 32; o > 0; o >>= 1) v += __shfl_xor(v, o);
    if ((tid & 63) == 0) sred[4 + wv] = v;
    __syncthreads();
    float s = sred[4] + sred[5] + sred[6] + sred[7];
    Wh[b * 256 + tid] = (_Float16)(e / s);
}

// K_B: coupling via MFMA (R6-R8 verified), B staged through LDS row-dense.
// grid (4, 128) = 512 blocks, 33KB LDS, 8 waves/CU. Epilogue trig via v_sin/v_cos.
__global__ __launch_bounds__(256) void k_coupling_mfma(const uint32_t* __restrict__ XPT,
                                                       const _Float16* __restrict__ Wh,
                                                       const float* __restrict__ phi,
                                                       const float* __restrict__ t_ptr,
                                                       float* __restrict__ out) {
    const int mt = blockIdx.x;                             // 0..3
    const int ctg = blockIdx.y;                            // 0..127
    const int tid = threadIdx.x;
    const int w = tid >> 6;
    const int lane = tid & 63;
    const int cl = lane & 15;
    const int q  = lane >> 4;

    __shared__ uint32_t xs[32][260];                       // 32 rows, 1KB + 16B pad

    const int n0 = ctg * 32;
#pragma unroll
    for (int it = 0; it < 8; ++it) {
        int i = tid + it * 256;
        int row = i >> 6, seg = i & 63;
        uint4 v = *(const uint4*)&XPT[(n0 + row) * P_SZ + seg * 4];
        *(uint4*)&xs[row][seg * 4] = v;
    }
    __syncthreads();

    const int ct  = ctg * 4 + w;
    const int col = ct * 16 + cl;                          // 0..8191
    const int n   = col >> 1;
    const int n_l = w * 8 + (cl >> 1);                     // n - n0
    const int comp = col & 1;                              // 0=cos(lo), 1=sin(hi)
    const uint32_t sel = comp ? 0x07060302u : 0x05040100u;

    const _Float16* wrow = Wh + (mt * 16 + cl) * 256;      // A row b = mt*16+cl

    floatx4 acc = {0.f, 0.f, 0.f, 0.f};
#pragma unroll
    for (int s = 0; s < 8; ++s) {
        const int k0 = s * 32 + q * 8;                     // this lane's first p
        half8 af = *(const half8*)&wrow[k0];               // 16B, L2-hot (32KB table)
        uint4 v0 = *(const uint4*)&xs[n_l][k0];            // ds_read_b128
        uint4 v1 = *(const uint4*)&xs[n_l][k0 + 4];
        uint4 bi;
        bi.x = permsel(v0.y, v0.x, sel);
        bi.y = permsel(v0.w, v0.z, sel);
        bi.z = permsel(v1.y, v1.x, sel);
        bi.w = permsel(v1.w, v1.z, sel);
        half8 bf = __builtin_bit_cast(half8, bi);
        acc = __builtin_amdgcn_mfma_f32_16x16x32_f16(af, bf, acc, 0, 0, 0);
    }

    // D: col=lane&15, row(b-local)=q*4+r [verified]; pair cos/sin via xor(1)
    float aS0 = __shfl_xor(acc[0], 1);
    float aS1 = __shfl_xor(acc[1], 1);
    float aS2 = __shfl_xor(acc[2], 1);
    float aS3 = __shfl_xor(acc[3], 1);
    if (!comp) {
        const float wt_r = OMEGA_ANC * t_ptr[0] * INV_2PI; // anchor phase, revolutions
        float aC[4] = {acc[0], acc[1], acc[2], acc[3]};
        float aS[4] = {aS0, aS1, aS2, aS3};
#pragma unroll
        for (int r = 0; r < 4; ++r) {
            int b = mt * 16 + q * 4 + r;
            float ph = phi[b * N_SZ + n];
            float pr = ph * INV_2PI;                       // [0,1): no reduction
            float ss = vsin_r(pr), cc = vcos_r(pr);
            float anc = vsin_r(vfract(wt_r - pr));         // sin(wt - ph)
            out[b * N_SZ + n] = fmaf(A_ANC, anc, ss * aC[r] - cc * aS[r]);
        }
    }
}

extern "C" void kernel_launch(void* const* d_in, const int* in_sizes, int n_in,
                              void* d_out, int out_size, void* d_ws, size_t ws_size,
                              hipStream_t stream) {
    const float* t   = (const float*)d_in[0];
    const float* phi = (const float*)d_in[1];
    const float* xi  = (const float*)d_in[2];
    float* out = (float*)d_out;

    char* w = (char*)d_ws;
    uint32_t* XPT   = (uint32_t*)w;                        // N*P dwords    = 4 MB
    float* m_part   = (float*)(w + 4u * 1024 * 1024);      // 32*64*256 f32 = 2 MB
    _Float16* Wh    = (_Float16*)(w + 6u * 1024 * 1024);   // 64*256 f16    = 32 KB

    k_mpart_mfma<<<dim3(64, 8), 256, 0, stream>>>(phi, xi, XPT, m_part);
    k_weights<<<64, 256, 0, stream>>>(m_part, Wh);
    k_coupling_mfma<<<dim3(4, 128), 256, 0, stream>>>(XPT, Wh, phi, t, out);
}

// Round 10
// 75.680 us; speedup vs baseline: 1.7866x; 1.0029x over previous
//
#include <hip/hip_runtime.h>
#include <hip/hip_fp16.h>
#include <math.h>
#include <stdint.h>

#define B_SZ 64
#define P_SZ 256
#define N_SZ 4096
#define A_ANC 0.08f
#define OMEGA_ANC 1256.6370614359172f
#define INV_2PI 0.15915494309189535f

typedef _Float16 half8 __attribute__((ext_vector_type(8)));
typedef float floatx4 __attribute__((ext_vector_type(4)));

// raw v_sin/v_cos: D = sin(2*pi*r). Inputs pre-scaled by 1/2pi (args in [0,2pi)).
__device__ __forceinline__ float vsin_r(float r) {
#if __has_builtin(__builtin_amdgcn_sinf)
    return __builtin_amdgcn_sinf(r);
#else
    return __sinf(r * 6.283185307179586f);
#endif
}
__device__ __forceinline__ float vcos_r(float r) {
#if __has_builtin(__builtin_amdgcn_cosf)
    return __builtin_amdgcn_cosf(r);
#else
    return __cosf(r * 6.283185307179586f);
#endif
}
__device__ __forceinline__ float vfract(float r) {
#if __has_builtin(__builtin_amdgcn_fractf)
    return __builtin_amdgcn_fractf(r);
#else
    return r - floorf(r);
#endif
}
// {cos(x), sin(x)} packed to half2 dword in one v_cvt_pkrtz
__device__ __forceinline__ uint32_t cs_pack(float x) {
    float r = x * INV_2PI;
    return __builtin_bit_cast(uint32_t,
        __builtin_amdgcn_cvt_pkrtz(vcos_r(r), vsin_r(r)));
}

__device__ __forceinline__ uint32_t permsel(uint32_t hi, uint32_t lo, uint32_t sel) {
#if __has_builtin(__builtin_amdgcn_perm)
    return __builtin_amdgcn_perm(hi, lo, sel);
#else
    unsigned long long v = ((unsigned long long)hi << 32) | lo;
    uint32_t r = 0;
#pragma unroll
    for (int i = 0; i < 4; ++i)
        r |= (uint32_t)((v >> (8 * ((sel >> (8 * i)) & 7))) & 0xff) << (8 * i);
    return r;
#endif
}

// K1: m-GEMM via MFMA (R5-R9 verified math). Partial sums go straight into
// m_total[b][p] via atomicAdd (m_total pre-zeroed by a memset node) -- this
// deletes the k_weights kernel + m_part round trip entirely.
// bt==0 waves store B-frags to XPT[n][p] ({cos,sin} half2 dword), each (n,p) once.
// grid (64, 8) x 4 waves = 2048 waves = 8/CU. No LDS, no barriers.
__global__ __launch_bounds__(256) void k_mpart_mfma(const float* __restrict__ phi,
                                                    const float* __restrict__ xi,
                                                    uint32_t* __restrict__ XPT,
                                                    float* __restrict__ m_total) {
    const int bt = blockIdx.x & 3;          // b-tile (4 x 16)
    const int pt = blockIdx.x >> 2;         // p-tile (16 x 16)
    const int w  = threadIdx.x >> 6;
    const int lane = threadIdx.x & 63;
    const int m = lane & 15;
    const int q = lane >> 4;

    const int c  = blockIdx.y * 4 + w;      // K chunk 0..31 (128 n each)
    const int n0 = c * 128;
    const int b_row = bt * 16 + m;
    const int p_row = pt * 16 + m;

    floatx4 acc = {0.f, 0.f, 0.f, 0.f};
#pragma unroll
    for (int s = 0; s < 8; ++s) {
        const int nb = n0 + s * 16 + q * 4;                    // this lane's 4 n's
        float4 ph = *(const float4*)&phi[b_row * N_SZ + nb];   // A source (line-dense)
        float4 xv = *(const float4*)&xi[p_row * N_SZ + nb];    // B source (line-dense)
        uint4 ai, bi;
        ai.x = cs_pack(ph.x); ai.y = cs_pack(ph.y);
        ai.z = cs_pack(ph.z); ai.w = cs_pack(ph.w);
        bi.x = cs_pack(xv.x); bi.y = cs_pack(xv.y);
        bi.z = cs_pack(xv.z); bi.w = cs_pack(xv.w);
        if (bt == 0) {                                         // wave-uniform branch
            XPT[(nb + 0) * P_SZ + p_row] = bi.x;
            XPT[(nb + 1) * P_SZ + p_row] = bi.y;
            XPT[(nb + 2) * P_SZ + p_row] = bi.z;
            XPT[(nb + 3) * P_SZ + p_row] = bi.w;
        }
        half8 af = __builtin_bit_cast(half8, ai);
        half8 bf = __builtin_bit_cast(half8, bi);
        acc = __builtin_amdgcn_mfma_f32_16x16x32_f16(af, bf, acc, 0, 0, 0);
    }
    // D: col(p)=lane&15, row(b)=q*4+r [verified]; accumulate across chunks
#pragma unroll
    for (int r = 0; r < 4; ++r) {
        int b = bt * 16 + q * 4 + r;
        atomicAdd(&m_total[b * 256 + pt * 16 + m], acc[r]);
    }
}

// K2: in-block softmax + coupling MFMA + anchor (R6-R9 verified math).
// Softmax: wave w computes weight rows bl=w*4..w*4+3 for this block's mt from
// m_total (dwordx4 + 6-step shfl reductions, no barriers) into LDS f16 table.
// B staged through LDS row-dense (R8). One __syncthreads covers both.
// grid (4 mt, 128 ctg) = 512 blocks, ~41KB LDS, 8 waves/CU.
__global__ __launch_bounds__(256) void k_coupling_mfma(const uint32_t* __restrict__ XPT,
                                                       const float* __restrict__ m_total,
                                                       const float* __restrict__ phi,
                                                       const float* __restrict__ t_ptr,
                                                       float* __restrict__ out) {
    const int mt = blockIdx.x;                             // 0..3
    const int ctg = blockIdx.y;                            // 0..127
    const int tid = threadIdx.x;
    const int w = tid >> 6;
    const int lane = tid & 63;
    const int cl = lane & 15;
    const int q  = lane >> 4;

    __shared__ uint32_t xs[32][260];                       // 32 XPT rows + pad
    __shared__ _Float16 wh[16][264];                       // weight rows + pad

    const int n0 = ctg * 32;
#pragma unroll
    for (int it = 0; it < 8; ++it) {
        int i = tid + it * 256;
        int row = i >> 6, seg = i & 63;
        uint4 v = *(const uint4*)&XPT[(n0 + row) * P_SZ + seg * 4];
        *(uint4*)&xs[row][seg * 4] = v;
    }

    // softmax for this block's 16 b-rows; wave w owns bl = w*4..w*4+3
#pragma unroll
    for (int j = 0; j < 4; ++j) {
        const int bl = w * 4 + j;
        float4 v = *(const float4*)&m_total[(mt * 16 + bl) * 256 + lane * 4];
        float4 l = {v.x * (1.0f / 4096.0f), v.y * (1.0f / 4096.0f),
                    v.z * (1.0f / 4096.0f), v.w * (1.0f / 4096.0f)};
        float mx = fmaxf(fmaxf(l.x, l.y), fmaxf(l.z, l.w));
        for (int o = 32; o > 0; o >>= 1) mx = fmaxf(mx, __shfl_xor(mx, o));
        float e0 = __expf(l.x - mx), e1 = __expf(l.y - mx);
        float e2 = __expf(l.z - mx), e3 = __expf(l.w - mx);
        float s = e0 + e1 + e2 + e3;
        for (int o = 32; o > 0; o >>= 1) s += __shfl_xor(s, o);
        float rs = 1.0f / s;
        uint2 pk;
        pk.x = __builtin_bit_cast(uint32_t,
                 __builtin_amdgcn_cvt_pkrtz(e0 * rs, e1 * rs));
        pk.y = __builtin_bit_cast(uint32_t,
                 __builtin_amdgcn_cvt_pkrtz(e2 * rs, e3 * rs));
        *(uint2*)&wh[bl][lane * 4] = pk;                   // 8B ds_write
    }
    __syncthreads();

    const int ct  = ctg * 4 + w;
    const int col = ct * 16 + cl;                          // 0..8191
    const int n   = col >> 1;
    const int n_l = w * 8 + (cl >> 1);                     // n - n0
    const int comp = col & 1;                              // 0=cos(lo), 1=sin(hi)
    const uint32_t sel = comp ? 0x07060302u : 0x05040100u;

    floatx4 acc = {0.f, 0.f, 0.f, 0.f};
#pragma unroll
    for (int s = 0; s < 8; ++s) {
        const int k0 = s * 32 + q * 8;                     // this lane's first p
        half8 af = *(const half8*)&wh[cl][k0];             // LDS weight frag
        uint4 v0 = *(const uint4*)&xs[n_l][k0];            // ds_read_b128
        uint4 v1 = *(const uint4*)&xs[n_l][k0 + 4];
        uint4 bi;
        bi.x = permsel(v0.y, v0.x, sel);
        bi.y = permsel(v0.w, v0.z, sel);
        bi.z = permsel(v1.y, v1.x, sel);
        bi.w = permsel(v1.w, v1.z, sel);
        half8 bf = __builtin_bit_cast(half8, bi);
        acc = __builtin_amdgcn_mfma_f32_16x16x32_f16(af, bf, acc, 0, 0, 0);
    }

    // D: col=lane&15, row(b-local)=q*4+r [verified]; pair cos/sin via xor(1)
    float aS0 = __shfl_xor(acc[0], 1);
    float aS1 = __shfl_xor(acc[1], 1);
    float aS2 = __shfl_xor(acc[2], 1);
    float aS3 = __shfl_xor(acc[3], 1);
    if (!comp) {
        const float wt_r = OMEGA_ANC * t_ptr[0] * INV_2PI; // anchor phase, revolutions
        float aC[4] = {acc[0], acc[1], acc[2], acc[3]};
        float aS[4] = {aS0, aS1, aS2, aS3};
#pragma unroll
        for (int r = 0; r < 4; ++r) {
            int b = mt * 16 + q * 4 + r;
            float ph = phi[b * N_SZ + n];
            float pr = ph * INV_2PI;                       // [0,1): no reduction
            float ss = vsin_r(pr), cc = vcos_r(pr);
            float anc = vsin_r(vfract(wt_r - pr));         // sin(wt - ph)
            out[b * N_SZ + n] = fmaf(A_ANC, anc, ss * aC[r] - cc * aS[r]);
        }
    }
}

extern "C" void kernel_launch(void* const* d_in, const int* in_sizes, int n_in,
                              void* d_out, int out_size, void* d_ws, size_t ws_size,
                              hipStream_t stream) {
    const float* t   = (const float*)d_in[0];
    const float* phi = (const float*)d_in[1];
    const float* xi  = (const float*)d_in[2];
    float* out = (float*)d_out;

    char* w = (char*)d_ws;
    uint32_t* XPT   = (uint32_t*)w;                        // N*P dwords  = 4 MB
    float* m_total  = (float*)(w + 4u * 1024 * 1024);      // 64*256 f32  = 64 KB

    hipMemsetAsync(m_total, 0, B_SZ * P_SZ * sizeof(float), stream);
    k_mpart_mfma<<<dim3(64, 8), 256, 0, stream>>>(phi, xi, XPT, m_total);
    k_coupling_mfma<<<dim3(4, 128), 256, 0, stream>>>(XPT, m_total, phi, t, out);
}